// Round 10
// baseline (477.025 us; speedup 1.0000x reference)
//
#include <hip/hip_runtime.h>

// KNN top-16: B=4, N=M=8192, C=3.  (GOLD METRIC LOCKED by R17, absmax=0:
//   norms = (x²+z²)+y² [hsum, plain]; cross = fma(z,z',fma(y,y',x*x'));
//   d2 = max((q2+r2) - 2*cross, 0); stable (d2,idx) ascending; 0-based.)
// Session model (R20-R28): ~227us is the brute-force structure's floor —
//   issue ~150-165us + ~75us stall; occupancy pinned ~37% regardless of
//   waves (R9), LDS (R8), or VALU count (R26). Only total-work cuts remain.
// R29: norm-banded pruning. Prep kernel sorts refs by locked-chain r2 and
//   queries by q2 (per batch) into d_ws. Main kernel = the proven 227us
//   inner machinery (pk metric, u64 keys, persistent buffer, batched
//   compact, shfl merge, (128,4)+float4 staging) with:
//   - tiles = norm bands, visited circularly from the block's own band
//     (fill seeds T from nearest-in-norm points -> tight immediately);
//   - per-band wave skip when provably no lane qualifies:
//     real d2 >= (sqrt(r2)-|q|)^2, skip iff sqrt(lo)-|q| > sqrt(T)*1.001
//     + 0.01 (absolute margin >> worst-case fma-cancellation ~3e-5 =>
//     skip only provable misses, exactness preserved);
//   - appends store ORIGINAL idx via staged ti[] u16 -> keys/tie-break
//     byte-identical to reference.
//   Queries sorted => block's 16 queries share a narrow window.
//   Fallback to the verbatim R7 kernel if ws_size insufficient.

#define TPB 128
#define QPB 16   // queries per block
#define SPL 8    // threads per query
#define KK 16
#define TILE_PTS 512
#define NBANDS 16  // N / TILE_PTS at N=8192
#define CAP 14   // LDS candidate slots per thread (LDS budget: 19968 B)
#define TRIG 7   // compaction trigger (checked every 8; 6+8 <= 14 = CAP)

typedef unsigned long long u64k;
typedef float f32x2 __attribute__((ext_vector_type(2)));

__device__ __forceinline__ f32x2 pk_mul(f32x2 a, f32x2 b) {
  f32x2 d;
  asm("v_pk_mul_f32 %0, %1, %2" : "=v"(d) : "v"(a), "v"(b));
  return d;
}
__device__ __forceinline__ f32x2 pk_fma(f32x2 a, f32x2 b, f32x2 c) {
  f32x2 d;
  asm("v_pk_fma_f32 %0, %1, %2, %3" : "=v"(d) : "v"(a), "v"(b), "v"(c));
  return d;
}
__device__ __forceinline__ f32x2 pk_add(f32x2 a, f32x2 b) {
  f32x2 d;
  asm("v_pk_add_f32 %0, %1, %2" : "=v"(d) : "v"(a), "v"(b));
  return d;
}

#define CE(x, i, j)                                   \
  {                                                   \
    u64k ki_ = x[i], kj_ = x[j];                      \
    bool c_ = kj_ < ki_;                              \
    x[i] = c_ ? kj_ : ki_;                            \
    x[j] = c_ ? ki_ : kj_;                            \
  }

// Batcher odd-even mergesort, 16 elements, 63 comparators.
__device__ __forceinline__ void sort16(u64k x[KK]) {
  CE(x,0,1) CE(x,2,3) CE(x,4,5) CE(x,6,7) CE(x,8,9) CE(x,10,11) CE(x,12,13) CE(x,14,15)
  CE(x,0,2) CE(x,1,3) CE(x,4,6) CE(x,5,7) CE(x,8,10) CE(x,9,11) CE(x,12,14) CE(x,13,15)
  CE(x,1,2) CE(x,5,6) CE(x,9,10) CE(x,13,14)
  CE(x,0,4) CE(x,1,5) CE(x,2,6) CE(x,3,7) CE(x,8,12) CE(x,9,13) CE(x,10,14) CE(x,11,15)
  CE(x,2,4) CE(x,3,5) CE(x,10,12) CE(x,11,13)
  CE(x,1,2) CE(x,3,4) CE(x,5,6) CE(x,9,10) CE(x,11,12) CE(x,13,14)
  CE(x,0,8) CE(x,1,9) CE(x,2,10) CE(x,3,11) CE(x,4,12) CE(x,5,13) CE(x,6,14) CE(x,7,15)
  CE(x,4,8) CE(x,5,9) CE(x,6,10) CE(x,7,11)
  CE(x,2,4) CE(x,3,5) CE(x,6,8) CE(x,7,9) CE(x,10,12) CE(x,11,13)
  CE(x,1,2) CE(x,3,4) CE(x,5,6) CE(x,7,8) CE(x,9,10) CE(x,11,12) CE(x,13,14)
}

// a asc, e asc -> a = 16 smallest of (a ∪ e), ascending.
__device__ __forceinline__ void mergeTop16(u64k a[KK], u64k e[KK]) {
#pragma unroll
  for (int i = 0; i < KK; ++i) {
    u64k bv = e[KK - 1 - i];
    if (bv < a[i]) a[i] = bv;
  }
  // bitonic clean (distances 8,4,2,1)
  CE(a,0,8) CE(a,1,9) CE(a,2,10) CE(a,3,11) CE(a,4,12) CE(a,5,13) CE(a,6,14) CE(a,7,15)
  CE(a,0,4) CE(a,1,5) CE(a,2,6) CE(a,3,7) CE(a,8,12) CE(a,9,13) CE(a,10,14) CE(a,11,15)
  CE(a,0,2) CE(a,1,3) CE(a,4,6) CE(a,5,7) CE(a,8,10) CE(a,9,11) CE(a,12,14) CE(a,13,15)
  CE(a,0,1) CE(a,2,3) CE(a,4,5) CE(a,6,7) CE(a,8,9) CE(a,10,11) CE(a,12,13) CE(a,14,15)
}

// ---------------- prep: per-batch bitonic sorts into d_ws ----------------

__device__ __forceinline__ void bitonic8192(u64k* sh, int tid) {
  for (int k = 2; k <= 8192; k <<= 1) {
    for (int j = k >> 1; j > 0; j >>= 1) {
      for (int i = tid; i < 8192; i += 512) {
        int ixj = i ^ j;
        if (ixj > i) {
          u64k a = sh[i], c = sh[ixj];
          if ((a > c) == ((i & k) == 0)) {
            sh[i] = c;
            sh[ixj] = a;
          }
        }
      }
      __syncthreads();
    }
  }
}

__global__ __launch_bounds__(512) void knn_prep(
    const float* __restrict__ ref, const float* __restrict__ query,
    float4* __restrict__ srt, unsigned* __restrict__ sidx,
    unsigned* __restrict__ qperm, int N, int M) {
#pragma clang fp contract(off)
  __shared__ u64k sh[8192];  // 64 KB
  const int tid = threadIdx.x;
  const int g = blockIdx.x;
  if (g < 4) {
    // sort refs of batch g by locked-chain r2 (key = r2bits<<32 | idx)
    const float* rb = ref + (size_t)g * N * 3;
    for (int i = tid; i < N; i += 512) {
      float x = rb[3 * i], y = rb[3 * i + 1], z = rb[3 * i + 2];
      float r2 = (x * x + z * z) + y * y;  // locked norm chain
      sh[i] = ((u64k)__float_as_uint(r2) << 32) | (unsigned)i;
    }
    __syncthreads();
    bitonic8192(sh, tid);
    for (int s = tid; s < N; s += 512) {
      u64k key = sh[s];
      unsigned oi = (unsigned)key;
      srt[(size_t)g * N + s] =
          make_float4(rb[3 * oi], rb[3 * oi + 1], rb[3 * oi + 2],
                      __uint_as_float((unsigned)(key >> 32)));
      sidx[(size_t)g * N + s] = oi;
    }
  } else {
    // sort queries of batch g-4 by q2 (permutation only)
    const int qb = g - 4;
    const float* qbp = query + (size_t)qb * M * 3;
    for (int i = tid; i < M; i += 512) {
      float x = qbp[3 * i], y = qbp[3 * i + 1], z = qbp[3 * i + 2];
      float q2 = (x * x + z * z) + y * y;
      sh[i] = ((u64k)__float_as_uint(q2) << 32) | (unsigned)i;
    }
    __syncthreads();
    bitonic8192(sh, tid);
    for (int s = tid; s < M; s += 512)
      qperm[(size_t)qb * M + s] = (unsigned)(qb * M) + (unsigned)sh[s];
  }
}

// ---------------- main: norm-banded search ----------------

__global__ __launch_bounds__(TPB, 4) void knn_main(
    const float4* __restrict__ srt, const unsigned* __restrict__ sidx,
    const unsigned* __restrict__ qperm, const float* __restrict__ query,
    float* __restrict__ dout, float* __restrict__ iout, int N, int M) {
#pragma clang fp contract(off)
  // SoA tile (swizzled as in the 227us kernel) + staged original indices.
  __shared__ float tx[TILE_PTS], ty[TILE_PTS], tz[TILE_PTS], tw[TILE_PTS];
  __shared__ unsigned short ti[TILE_PTS];   // 1 KB: original idx per slot
  __shared__ unsigned int sd[CAP * TPB];    // 7 KB: candidate d2bits
  __shared__ unsigned short sg[CAP * TPB];  // 3.5 KB: candidate ORIGINAL idx

  float4* tx4 = (float4*)tx;
  float4* ty4 = (float4*)ty;
  float4* tz4 = (float4*)tz;
  float4* tw4 = (float4*)tw;

  const int tid = threadIdx.x;
  const int h = tid & (SPL - 1);
  const int slot = blockIdx.x * QPB + (tid >> 3);  // sorted query slot
  const int b = (blockIdx.x * QPB) / M;            // batch (uniform: M%QPB==0)

  const unsigned orig = qperm[slot];  // original global qid
  const float* qp = query + (size_t)orig * 3;
  const float qx = qp[0], qy = qp[1], qz = qp[2];
  const float q2 = (qx * qx + qz * qz) + qy * qy;  // locked chain
  const float qn = sqrtf(q2);
  const f32x2 qxx = {qx, qx}, qyy = {qy, qy}, qzz = {qz, qz};
  const f32x2 q22 = {q2, q2}, n22 = {-2.0f, -2.0f};

  u64k kl[KK];       // sorted ascending (d2bits<<32 | orig_idx)
  float T = 3.0e38f; // shared screen threshold (min of 8 threads' 16th)
  float Ts = 1.8e19f;  // sqrt(T) with conservative margin
  int cnt = 0;

  const float4* sb = srt + (size_t)b * N;
  const unsigned* sib = sidx + (size_t)b * N;

  auto refreshT = [&]() {
    float a15 = __uint_as_float((unsigned)(kl[KK - 1] >> 32));
    float m = fminf(a15, __shfl_xor(a15, 1));
    m = fminf(m, __shfl_xor(m, 2));
    T = fminf(m, __shfl_xor(m, 4));
    // margin: rel 1e-3 + abs 1e-2 >> worst-case f32 fma-cancellation (~3e-5)
    Ts = sqrtf(T) * 1.001f + 0.01f;
  };

  auto compact = [&]() {
    u64k e[KK];
#pragma unroll
    for (int s = 0; s < KK; ++s) {
      u64k key = ~0ull;
      if (s < CAP) {
        unsigned db = sd[s * TPB + tid];
        unsigned gi = sg[s * TPB + tid];
        key = ((u64k)db << 32) | gi;
      }
      e[s] = (s < cnt) ? key : ~0ull;
    }
    sort16(e);
    mergeTop16(kl, e);
    cnt = 0;
    refreshT();
  };

  // Packed metric for 4 consecutive points of this thread's sub-band.
  auto evalg = [&](int j, f32x2& d01, f32x2& d23, ushort4& tv) {
    int ridx = (h << 4) + (j ^ h);
    float4 xs = tx4[ridx];
    float4 ys = ty4[ridx];
    float4 zs = tz4[ridx];
    float4 ws = tw4[ridx];
    tv = ((const ushort4*)ti)[ridx];
    f32x2 x01 = {xs.x, xs.y}, x23 = {xs.z, xs.w};
    f32x2 y01 = {ys.x, ys.y}, y23 = {ys.z, ys.w};
    f32x2 z01 = {zs.x, zs.y}, z23 = {zs.z, zs.w};
    f32x2 w01 = {ws.x, ws.y}, w23 = {ws.z, ws.w};
    f32x2 cr01 = pk_mul(qxx, x01);
    cr01 = pk_fma(qyy, y01, cr01);
    cr01 = pk_fma(qzz, z01, cr01);
    f32x2 s01 = pk_add(q22, w01);
    d01 = pk_fma(n22, cr01, s01);
    f32x2 cr23 = pk_mul(qxx, x23);
    cr23 = pk_fma(qyy, y23, cr23);
    cr23 = pk_fma(qzz, z23, cr23);
    f32x2 s23 = pk_add(q22, w23);
    d23 = pk_fma(n22, cr23, s23);
  };

  auto app = [&](float d2, unsigned short oi) {
    if (d2 <= T) {  // conservative shared screen (<= keeps exact ties)
      float d2c = d2 < 0.f ? 0.f : d2;
      sd[cnt * TPB + tid] = __float_as_uint(d2c);
      sg[cnt * TPB + tid] = oi;
      cnt++;
    }
  };

  // Block-uniform center band from the block's first query.
  float q2f;
  {
    unsigned o0 = qperm[blockIdx.x * QPB];
    const float* q0 = query + (size_t)o0 * 3;
    float ax = q0[0], ay = q0[1], az = q0[2];
    q2f = (ax * ax + az * az) + ay * ay;
  }
  int cband = 0;
  for (int k2 = 1; k2 < NBANDS; ++k2)
    cband += (sb[(size_t)k2 * TILE_PTS].w <= q2f) ? 1 : 0;

  for (int it = 0; it < NBANDS; ++it) {
    const int band = (cband + it) & (NBANDS - 1);
    __syncthreads();
    {
      // Stage 4 sorted points/thread (AoS float4, aligned) + orig idx;
      // transpose to SoA in regs; proven swizzled writes.
      int pl = tid * 4;
      const float4* rp = sb + (size_t)band * TILE_PTS + pl;
      float4 p0 = rp[0], p1 = rp[1], p2 = rp[2], p3 = rp[3];
      const unsigned* ip = sib + (size_t)band * TILE_PTS + pl;
      unsigned i0 = ip[0], i1 = ip[1], i2 = ip[2], i3 = ip[3];
      int widx = ((tid >> 4) << 4) + ((tid & 15) ^ (tid >> 4));
      tx4[widx] = make_float4(p0.x, p1.x, p2.x, p3.x);
      ty4[widx] = make_float4(p0.y, p1.y, p2.y, p3.y);
      tz4[widx] = make_float4(p0.z, p1.z, p2.z, p3.z);
      tw4[widx] = make_float4(p0.w, p1.w, p2.w, p3.w);
      ((ushort4*)ti)[widx] =
          make_ushort4((unsigned short)i0, (unsigned short)i1,
                       (unsigned short)i2, (unsigned short)i3);
    }
    __syncthreads();
    if (it == 0) {
      // Fill from the nearest-in-norm band: exact chain, one sort -> tight T.
#pragma unroll
      for (int j = 0; j < 4; ++j) {
        f32x2 d01, d23;
        ushort4 tv;
        evalg(j, d01, d23, tv);
        float v0 = d01.x < 0.f ? 0.f : d01.x;
        float v1 = d01.y < 0.f ? 0.f : d01.y;
        float v2 = d23.x < 0.f ? 0.f : d23.x;
        float v3 = d23.y < 0.f ? 0.f : d23.y;
        kl[j * 4 + 0] = ((u64k)__float_as_uint(v0) << 32) | tv.x;
        kl[j * 4 + 1] = ((u64k)__float_as_uint(v1) << 32) | tv.y;
        kl[j * 4 + 2] = ((u64k)__float_as_uint(v2) << 32) | tv.z;
        kl[j * 4 + 3] = ((u64k)__float_as_uint(v3) << 32) | tv.w;
      }
      sort16(kl);
      refreshT();
      for (int j = 4; j < 16; j += 2) {
        {
          f32x2 d01, d23;
          ushort4 tv;
          evalg(j, d01, d23, tv);
          app(d01.x, tv.x);
          app(d01.y, tv.y);
          app(d23.x, tv.z);
          app(d23.y, tv.w);
        }
        {
          f32x2 d01, d23;
          ushort4 tv;
          evalg(j + 1, d01, d23, tv);
          app(d01.x, tv.x);
          app(d01.y, tv.y);
          app(d23.x, tv.z);
          app(d23.y, tv.w);
        }
        if (__any(cnt >= TRIG)) compact();  // wave-synchronized
      }
    } else {
      // Band skip: provable-miss only (real d2 >= (sqrt(r2)-|q|)^2).
      float lo = sb[(size_t)band * TILE_PTS].w;
      float hi = sb[(size_t)band * TILE_PTS + TILE_PTS - 1].w;
      bool skip = (q2 < lo) ? ((sqrtf(lo) - qn) > Ts)
                            : ((q2 > hi) ? ((qn - sqrtf(hi)) > Ts) : false);
      if (__any(!skip)) {
        for (int j = 0; j < 16; j += 2) {
          {
            f32x2 d01, d23;
            ushort4 tv;
            evalg(j, d01, d23, tv);
            app(d01.x, tv.x);
            app(d01.y, tv.y);
            app(d23.x, tv.z);
            app(d23.y, tv.w);
          }
          {
            f32x2 d01, d23;
            ushort4 tv;
            evalg(j + 1, d01, d23, tv);
            app(d01.x, tv.x);
            app(d01.y, tv.y);
            app(d23.x, tv.z);
            app(d23.y, tv.w);
          }
          if (__any(cnt >= TRIG)) compact();  // wave-synchronized
        }
      }
    }
  }
  if (__any(cnt > 0)) compact();  // resolve stragglers

  // Cross-lane tree merge over the 8 subset threads.
#pragma unroll
  for (int d = 1; d < SPL; d <<= 1) {
    u64k r[KK];
#pragma unroll
    for (int s = 0; s < KK; ++s) r[s] = __shfl_xor(kl[s], d);
    mergeTop16(kl, r);
  }

  if (h == 0) {
    float* dq = dout + (size_t)orig * KK;
    float* iq = iout + (size_t)orig * KK;
    float dv[KK], iv[KK];
#pragma unroll
    for (int o = 0; o < KK; ++o) {
      dv[o] = sqrtf(__uint_as_float((unsigned)(kl[o] >> 32)));
      iv[o] = (float)(unsigned)(kl[o] & 0xffffffffu);  // 0-based orig idx
    }
    ((float4*)dq)[0] = make_float4(dv[0], dv[1], dv[2], dv[3]);
    ((float4*)dq)[1] = make_float4(dv[4], dv[5], dv[6], dv[7]);
    ((float4*)dq)[2] = make_float4(dv[8], dv[9], dv[10], dv[11]);
    ((float4*)dq)[3] = make_float4(dv[12], dv[13], dv[14], dv[15]);
    ((float4*)iq)[0] = make_float4(iv[0], iv[1], iv[2], iv[3]);
    ((float4*)iq)[1] = make_float4(iv[4], iv[5], iv[6], iv[7]);
    ((float4*)iq)[2] = make_float4(iv[8], iv[9], iv[10], iv[11]);
    ((float4*)iq)[3] = make_float4(iv[12], iv[13], iv[14], iv[15]);
  }
}

// ---------------- legacy fallback: the verified 227us kernel ----------------

__global__ __launch_bounds__(TPB, 4) void knn_legacy(
    const float* __restrict__ ref, const float* __restrict__ query,
    float* __restrict__ dout, float* __restrict__ iout, int N, int M) {
#pragma clang fp contract(off)
  __shared__ float tx[TILE_PTS], ty[TILE_PTS], tz[TILE_PTS], tw[TILE_PTS];
  __shared__ unsigned int sd[16 * TPB];
  __shared__ unsigned short sg[16 * TPB];

  float4* tx4 = (float4*)tx;
  float4* ty4 = (float4*)ty;
  float4* tz4 = (float4*)tz;
  float4* tw4 = (float4*)tw;

  const int tid = threadIdx.x;
  const int h = tid & (SPL - 1);
  const int qid = blockIdx.x * QPB + (tid >> 3);
  const int b = qid / M;

  const float* qp = query + (size_t)qid * 3;
  const float qx = qp[0], qy = qp[1], qz = qp[2];
  const float q2 = (qx * qx + qz * qz) + qy * qy;
  const f32x2 qxx = {qx, qx}, qyy = {qy, qy}, qzz = {qz, qz};
  const f32x2 q22 = {q2, q2}, n22 = {-2.0f, -2.0f};

  u64k kl[KK];
  float T = 3.0e38f;
  int cnt = 0;

  const float* refb = ref + (size_t)b * N * 3;

  auto refreshT = [&]() {
    float a15 = __uint_as_float((unsigned)(kl[KK - 1] >> 32));
    float m = fminf(a15, __shfl_xor(a15, 1));
    m = fminf(m, __shfl_xor(m, 2));
    T = fminf(m, __shfl_xor(m, 4));
  };

  auto compact = [&]() {
    u64k e[KK];
#pragma unroll
    for (int s = 0; s < KK; ++s) {
      unsigned int db = sd[s * TPB + tid];
      unsigned int gi = sg[s * TPB + tid];
      u64k key = ((u64k)db << 32) | gi;
      e[s] = (s < cnt) ? key : ~0ull;
    }
    sort16(e);
    mergeTop16(kl, e);
    cnt = 0;
    refreshT();
  };

  auto evalg = [&](int j, f32x2& d01, f32x2& d23) {
    int ridx = (h << 4) + (j ^ h);
    float4 xs = tx4[ridx];
    float4 ys = ty4[ridx];
    float4 zs = tz4[ridx];
    float4 ws = tw4[ridx];
    f32x2 x01 = {xs.x, xs.y}, x23 = {xs.z, xs.w};
    f32x2 y01 = {ys.x, ys.y}, y23 = {ys.z, ys.w};
    f32x2 z01 = {zs.x, zs.y}, z23 = {zs.z, zs.w};
    f32x2 w01 = {ws.x, ws.y}, w23 = {ws.z, ws.w};
    f32x2 cr01 = pk_mul(qxx, x01);
    cr01 = pk_fma(qyy, y01, cr01);
    cr01 = pk_fma(qzz, z01, cr01);
    f32x2 s01 = pk_add(q22, w01);
    d01 = pk_fma(n22, cr01, s01);
    f32x2 cr23 = pk_mul(qxx, x23);
    cr23 = pk_fma(qyy, y23, cr23);
    cr23 = pk_fma(qzz, z23, cr23);
    f32x2 s23 = pk_add(q22, w23);
    d23 = pk_fma(n22, cr23, s23);
  };

  auto app = [&](float d2, int gi) {
    if (d2 <= T) {
      float d2c = d2 < 0.f ? 0.f : d2;
      sd[cnt * TPB + tid] = __float_as_uint(d2c);
      sg[cnt * TPB + tid] = (unsigned short)gi;
      cnt++;
    }
  };

  const int ntiles = N / TILE_PTS;
  for (int t = 0; t < ntiles; ++t) {
    __syncthreads();
    {
      int pl = tid * 4;
      const float4* rp =
          (const float4*)(refb + (size_t)(t * TILE_PTS + pl) * 3);
      float4 f0 = rp[0], f1 = rp[1], f2 = rp[2];
      float x0 = f0.x, y0 = f0.y, z0 = f0.z;
      float x1 = f0.w, y1 = f1.x, z1 = f1.y;
      float x2 = f1.z, y2 = f1.w, z2 = f2.x;
      float x3 = f2.y, y3 = f2.z, z3 = f2.w;
      int widx = ((tid >> 4) << 4) + ((tid & 15) ^ (tid >> 4));
      tx4[widx] = make_float4(x0, x1, x2, x3);
      ty4[widx] = make_float4(y0, y1, y2, y3);
      tz4[widx] = make_float4(z0, z1, z2, z3);
      tw4[widx] = make_float4((x0 * x0 + z0 * z0) + y0 * y0,
                              (x1 * x1 + z1 * z1) + y1 * y1,
                              (x2 * x2 + z2 * z2) + y2 * y2,
                              (x3 * x3 + z3 * z3) + y3 * y3);
    }
    __syncthreads();
    const int tbase = t * TILE_PTS;
    int j0 = 0;
    if (t == 0) {
#pragma unroll
      for (int j = 0; j < 4; ++j) {
        f32x2 d01, d23;
        evalg(j, d01, d23);
        int gb = (h << 6) + (j << 2);
        float v0 = d01.x < 0.f ? 0.f : d01.x;
        float v1 = d01.y < 0.f ? 0.f : d01.y;
        float v2 = d23.x < 0.f ? 0.f : d23.x;
        float v3 = d23.y < 0.f ? 0.f : d23.y;
        kl[j * 4 + 0] = ((u64k)__float_as_uint(v0) << 32) | (unsigned)(gb + 0);
        kl[j * 4 + 1] = ((u64k)__float_as_uint(v1) << 32) | (unsigned)(gb + 1);
        kl[j * 4 + 2] = ((u64k)__float_as_uint(v2) << 32) | (unsigned)(gb + 2);
        kl[j * 4 + 3] = ((u64k)__float_as_uint(v3) << 32) | (unsigned)(gb + 3);
      }
      sort16(kl);
      refreshT();
      j0 = 4;
    }
    for (int j = j0; j < 16; j += 2) {
      {
        f32x2 d01, d23;
        evalg(j, d01, d23);
        int gb = tbase + (h << 6) + (j << 2);
        app(d01.x, gb + 0);
        app(d01.y, gb + 1);
        app(d23.x, gb + 2);
        app(d23.y, gb + 3);
      }
      {
        f32x2 d01, d23;
        evalg(j + 1, d01, d23);
        int gb = tbase + (h << 6) + ((j + 1) << 2);
        app(d01.x, gb + 0);
        app(d01.y, gb + 1);
        app(d23.x, gb + 2);
        app(d23.y, gb + 3);
      }
      if (__any(cnt >= 8)) compact();
    }
  }
  if (__any(cnt > 0)) compact();

#pragma unroll
  for (int d = 1; d < SPL; d <<= 1) {
    u64k r[KK];
#pragma unroll
    for (int s = 0; s < KK; ++s) r[s] = __shfl_xor(kl[s], d);
    mergeTop16(kl, r);
  }

  if (h == 0) {
    float* dq = dout + (size_t)qid * KK;
    float* iq = iout + (size_t)qid * KK;
    float dv[KK], iv[KK];
#pragma unroll
    for (int o = 0; o < KK; ++o) {
      dv[o] = sqrtf(__uint_as_float((unsigned)(kl[o] >> 32)));
      iv[o] = (float)(unsigned)(kl[o] & 0xffffffffu);
    }
    ((float4*)dq)[0] = make_float4(dv[0], dv[1], dv[2], dv[3]);
    ((float4*)dq)[1] = make_float4(dv[4], dv[5], dv[6], dv[7]);
    ((float4*)dq)[2] = make_float4(dv[8], dv[9], dv[10], dv[11]);
    ((float4*)dq)[3] = make_float4(dv[12], dv[13], dv[14], dv[15]);
    ((float4*)iq)[0] = make_float4(iv[0], iv[1], iv[2], iv[3]);
    ((float4*)iq)[1] = make_float4(iv[4], iv[5], iv[6], iv[7]);
    ((float4*)iq)[2] = make_float4(iv[8], iv[9], iv[10], iv[11]);
    ((float4*)iq)[3] = make_float4(iv[12], iv[13], iv[14], iv[15]);
  }
}

extern "C" void kernel_launch(void* const* d_in, const int* in_sizes, int n_in,
                              void* d_out, int out_size, void* d_ws, size_t ws_size,
                              hipStream_t stream) {
  const float* ref = (const float*)d_in[0];
  const float* query = (const float*)d_in[1];
  const int B = 4, C = 3;
  int N = in_sizes[0] / (B * C);
  int M = in_sizes[1] / (B * C);
  float* dout = (float*)d_out;
  float* iout = dout + (size_t)out_size / 2;  // idx half, written as float
  int totalQ = B * M;
  int blocks = totalQ / QPB;
  size_t srt_bytes = (size_t)B * N * sizeof(float4);
  size_t sidx_bytes = (size_t)B * N * sizeof(unsigned);
  size_t qperm_bytes = (size_t)totalQ * sizeof(unsigned);
  size_t need = srt_bytes + sidx_bytes + qperm_bytes;  // 768 KB
  if (N == 8192 && M == 8192 && d_ws != nullptr && ws_size >= need) {
    float4* srt = (float4*)d_ws;
    unsigned* sidxp = (unsigned*)((char*)d_ws + srt_bytes);
    unsigned* qpermp = (unsigned*)((char*)d_ws + srt_bytes + sidx_bytes);
    knn_prep<<<8, 512, 0, stream>>>(ref, query, srt, sidxp, qpermp, N, M);
    knn_main<<<blocks, TPB, 0, stream>>>(srt, sidxp, qpermp, query, dout, iout,
                                         N, M);
  } else {
    knn_legacy<<<blocks, TPB, 0, stream>>>(ref, query, dout, iout, N, M);
  }
}